// Round 10
// baseline (487.081 us; speedup 1.0000x reference)
//
#include <hip/hip_runtime.h>

#define DH 128

typedef __attribute__((ext_vector_type(8))) short short8;
typedef __attribute__((ext_vector_type(4))) float f32x4;

// ---------- helpers ----------
__device__ __forceinline__ float wave_sum(float v) {
    #pragma unroll
    for (int o = 32; o > 0; o >>= 1) v += __shfl_xor(v, o, 64);
    return v;
}

// LN over 128 cols; each of 64 lanes holds 4 cols, data duplicated across wave halves
__device__ __forceinline__ void ln_quad(float4 v, float4& o) {
    float m = wave_sum(v.x + v.y + v.z + v.w) * (1.f / 256.f);
    float dx = v.x - m, dy = v.y - m, dz = v.z - m, dw = v.w - m;
    float var = wave_sum(dx * dx + dy * dy + dz * dz + dw * dw) * (1.f / 256.f);
    float inv = rsqrtf(var + 1e-5f);
    o = make_float4(dx * inv, dy * inv, dz * inv, dw * inv);
}

__device__ __forceinline__ void ln_pair(float v0, float v1, float& o0, float& o1) {
    float m = wave_sum(v0 + v1) * (1.f / 128.f);
    float d0 = v0 - m, d1 = v1 - m;
    float var = wave_sum(d0 * d0 + d1 * d1) * (1.f / 128.f);
    float inv = rsqrtf(var + 1e-5f);
    o0 = d0 * inv; o1 = d1 * inv;
}

__device__ __forceinline__ float elu(float x) { return x > 0.f ? x : expm1f(x); }

// fp32 -> bf16 round-to-nearest-even
__device__ __forceinline__ unsigned short f2bf(float f) {
    unsigned u = __float_as_uint(f);
    u += 0x7fffu + ((u >> 16) & 1u);
    return (unsigned short)(u >> 16);
}
__device__ __forceinline__ float bfl(unsigned u) { return __uint_as_float(u << 16); }
__device__ __forceinline__ float bfh(unsigned u) { return __uint_as_float(u & 0xffff0000u); }
__device__ __forceinline__ unsigned pack_bf2(float a, float b) {
    return (unsigned)f2bf(a) | ((unsigned)f2bf(b) << 16);
}
__device__ __forceinline__ short8 cvt8(float4 v0, float4 v1) {
    short8 o;
    o[0] = (short)f2bf(v0.x); o[1] = (short)f2bf(v0.y);
    o[2] = (short)f2bf(v0.z); o[3] = (short)f2bf(v0.w);
    o[4] = (short)f2bf(v1.x); o[5] = (short)f2bf(v1.y);
    o[6] = (short)f2bf(v1.z); o[7] = (short)f2bf(v1.w);
    return o;
}

// ---------- streaming fp32 -> bf16 conversion of x (also zeroes deg) ----------
__global__ __launch_bounds__(256) void conv_x_k(const float* __restrict__ x,
                                                unsigned short* __restrict__ xb,
                                                long long n8, int* __restrict__ deg, int n)
{
    long long i = (long long)blockIdx.x * 256 + threadIdx.x;
    if (i < n) deg[i] = 0;
    long long stride = (long long)gridDim.x * 256;
    for (; i < n8; i += stride) {
        float4 v0 = *(const float4*)(x + i * 8);
        float4 v1 = *(const float4*)(x + i * 8 + 4);
        *(short8*)(xb + i * 8) = cvt8(v0, v1);
    }
}

// ---------- utility kernels ----------
__global__ void deg_count_k(const int* __restrict__ dst, int* __restrict__ deg, int E) {
    int e = blockIdx.x * 256 + threadIdx.x;
    if (e < E) atomicAdd(&deg[dst[e]], 1);
}

// ---------- parallel exclusive scan (3 kernels); also emits dinv ----------
__global__ __launch_bounds__(1024) void scan_part_k(const int* __restrict__ deg,
                                                    int* __restrict__ rowptr,
                                                    int* __restrict__ bsum,
                                                    float* __restrict__ dinv, int n)
{
    __shared__ int wsum[16];
    const int tid = threadIdx.x, lane = tid & 63, wid = tid >> 6;
    int i = blockIdx.x * 1024 + tid;
    int v = (i < n) ? deg[i] : 0;
    if (i < n) dinv[i] = rsqrtf((float)(v + 1));  // +1 self-loop
    int s = v;
    #pragma unroll
    for (int o = 1; o < 64; o <<= 1) {
        int t = __shfl_up(s, o, 64);
        if (lane >= o) s += t;
    }
    if (lane == 63) wsum[wid] = s;
    __syncthreads();
    if (tid < 16) {
        int ws = wsum[tid];
        #pragma unroll
        for (int o = 1; o < 16; o <<= 1) {
            int t = __shfl_up(ws, o, 64);
            if (tid >= o) ws += t;
        }
        wsum[tid] = ws;
    }
    __syncthreads();
    int excl = (wid ? wsum[wid - 1] : 0) + s - v;
    if (i < n) rowptr[i] = excl;
    if (tid == 0) bsum[blockIdx.x] = wsum[15];
}

__global__ void scan_top_k(int* __restrict__ bsum, int* __restrict__ rowptr_n, int nb) {
    int lane = threadIdx.x;  // blockDim = 64
    int carry = 0;
    for (int base = 0; base < nb; base += 64) {
        int i = base + lane;
        int v = (i < nb) ? bsum[i] : 0;
        int s = v;
        #pragma unroll
        for (int o = 1; o < 64; o <<= 1) {
            int t = __shfl_up(s, o, 64);
            if (lane >= o) s += t;
        }
        if (i < nb) bsum[i] = carry + s - v;
        carry += __shfl(s, 63, 64);
    }
    if (lane == 0) *rowptr_n = carry;
}

__global__ void scan_add_k(const int* __restrict__ bsum, int* __restrict__ rowptr,
                           int* __restrict__ cursor, int n)
{
    int i = blockIdx.x * 256 + threadIdx.x;
    if (i < n) {
        int v = rowptr[i] + bsum[i >> 10];
        rowptr[i] = v;
        cursor[i] = v;
    }
}

__global__ void fill_k(const int* __restrict__ src, const int* __restrict__ dst,
                       const float* __restrict__ dinv, int* __restrict__ cursor,
                       int2* __restrict__ csr, int E)
{
    int e = blockIdx.x * 256 + threadIdx.x;
    if (e < E) {
        int s = src[e], d = dst[e];
        float w = dinv[s] * dinv[d];
        int p = atomicAdd(&cursor[d], 1);
        csr[p] = make_int2(s, __float_as_int(w));
    }
}

// repack all four W's fp32 -> bf16 fragment panels [kb][n][32] into one buffer
__global__ void repack_all_k(const float* __restrict__ W1, const float* __restrict__ rW,
                             const float* __restrict__ W2, const float* __restrict__ mW1,
                             unsigned short* __restrict__ Wp)
{
    int idx = blockIdx.x * 256 + threadIdx.x;
    if (idx >= 131072) return;
    const float* W; int base;
    if (idx < 49152)       { W = W1;  base = 0; }
    else if (idx < 98304)  { W = rW;  base = 49152; }
    else if (idx < 114688) { W = W2;  base = 98304; }
    else                   { W = mW1; base = 114688; }
    int l = idx - base;
    int kb = l >> 12, rem = l & 4095;
    int nn = rem >> 5, ki = rem & 31;
    Wp[idx] = f2bf(W[(kb * 32 + ki) * DH + nn]);
}

// ---------- MFMA GEMM: B panel resident in LDS, barrier-free K-loop ----------
template<int K, int NMAT>
__global__ __launch_bounds__(256, 3) void mfma_gemm(
    const unsigned short* __restrict__ A,
    const unsigned short* __restrict__ Bp1, const float* __restrict__ ba,
    const unsigned short* __restrict__ Bp2, const float* __restrict__ bb,
    unsigned short* __restrict__ outa, unsigned short* __restrict__ outb, int n)
{
    constexpr int NKB = K / 32;
    constexpr int SB   = NKB * 64 * 32;
    constexpr int SEP  = 128 * 72;
    constexpr int SMEM = SB > SEP ? SB : SEP;
    __shared__ __align__(16) unsigned short smem[SMEM];

    const int tid = threadIdx.x;
    const int wid = tid >> 6, lane = tid & 63;
    const int m16 = lane & 15, q = lane >> 4;
    const int mat = (NMAT == 2) ? (int)(blockIdx.y >> 1) : 0;
    const int c0  = (blockIdx.y & 1) * 64;
    const unsigned short* Bp = mat ? Bp2 : Bp1;
    unsigned short* outp = mat ? outb : outa;
    const float* bias = mat ? bb : ba;
    const long long rowbase = (long long)blockIdx.x * 128;

    long long r0 = rowbase + wid * 32 + m16;       if (r0 > (long long)n - 1) r0 = n - 1;
    long long r1 = rowbase + wid * 32 + 16 + m16;  if (r1 > (long long)n - 1) r1 = n - 1;

    f32x4 acc[2][4];
    const f32x4 zero = {0.f, 0.f, 0.f, 0.f};
    #pragma unroll
    for (int mi = 0; mi < 2; ++mi)
        #pragma unroll
        for (int nj = 0; nj < 4; ++nj) acc[mi][nj] = zero;

    short8 ha[3][2];
    short8 bf[2][4];

    auto fetchA = [&](int kb, int buf) {
        ha[buf][0] = *(const short8*)(A + r0 * K + kb * 32 + q * 8);
        ha[buf][1] = *(const short8*)(A + r1 * K + kb * 32 + q * 8);
    };
    auto fetchB = [&](int kb, int buf) {
        #pragma unroll
        for (int nj = 0; nj < 4; ++nj)
            bf[buf][nj] = *(const short8*)(smem + kb * 2048 + (nj * 16 + m16) * 32 + q * 8);
    };

    fetchA(0, 0);
    if constexpr (NKB > 1) fetchA(1, 1);

    #pragma unroll
    for (int t = tid; t < K * 8; t += 256) {
        int k8 = t & 3, cl = (t >> 2) & 63, kb = t >> 8;
        *(short8*)(smem + kb * 2048 + cl * 32 + k8 * 8) =
            *(const short8*)(Bp + (long long)kb * 4096 + (c0 + cl) * 32 + k8 * 8);
    }
    __syncthreads();

    fetchB(0, 0);
    #pragma unroll
    for (int kb = 0; kb < NKB; ++kb) {
        if (kb + 2 < NKB) fetchA(kb + 2, (kb + 2) % 3);
        if (kb + 1 < NKB) fetchB(kb + 1, (kb + 1) & 1);
        const int ca = kb % 3, cb = kb & 1;
        #pragma unroll
        for (int mi = 0; mi < 2; ++mi)
            #pragma unroll
            for (int nj = 0; nj < 4; ++nj)
                acc[mi][nj] = __builtin_amdgcn_mfma_f32_16x16x32_bf16(ha[ca][mi], bf[cb][nj], acc[mi][nj], 0, 0, 0);
    }

    __syncthreads();
    #pragma unroll
    for (int nj = 0; nj < 4; ++nj) {
        int cl = nj * 16 + m16;
        float bv = bias ? bias[c0 + cl] : 0.f;
        #pragma unroll
        for (int mi = 0; mi < 2; ++mi)
            #pragma unroll
            for (int r = 0; r < 4; ++r)
                smem[(wid * 32 + mi * 16 + q * 4 + r) * 72 + cl] = f2bf(acc[mi][nj][r] + bv);
    }
    __syncthreads();
    #pragma unroll
    for (int h = 0; h < 4; ++h) {
        int idx = tid + h * 256;
        int row = idx >> 3, c8 = idx & 7;
        long long grow = rowbase + row;
        if (grow < n)
            *(short8*)(outp + grow * DH + c0 + c8 * 8) = *(const short8*)(smem + row * 72 + c8 * 8);
    }
}

// ---------- fused GEMM (K=128, full 128 cols) + LN/ELU + mW2 + softmax ----------
// grid ceil(n/64). Block: 64 rows x 128 cols. Wave w: rows (w>>1)*32..+32, cols (w&1)*64..+64.
__global__ __launch_bounds__(256, 3) void gemm_head_k(
    const unsigned short* __restrict__ A, const unsigned short* __restrict__ Bp,
    const float* __restrict__ mb1,
    const float* __restrict__ g, const float* __restrict__ be,
    const float* __restrict__ mW2, const float* __restrict__ mb2,
    float* __restrict__ out, int n)
{
    __shared__ __align__(16) unsigned short smem[16384];   // B: 4kb x 128col x 32k (32 KB)
    const int tid = threadIdx.x;
    const int wid = tid >> 6, lane = tid & 63;
    const int m16 = lane & 15, q = lane >> 4;
    const int rh = wid >> 1, ch = wid & 1;
    const long long rowbase = (long long)blockIdx.x * 64;

    long long r0 = rowbase + rh * 32 + m16;       if (r0 > (long long)n - 1) r0 = n - 1;
    long long r1 = rowbase + rh * 32 + 16 + m16;  if (r1 > (long long)n - 1) r1 = n - 1;

    f32x4 acc[2][4];
    const f32x4 zero = {0.f, 0.f, 0.f, 0.f};
    #pragma unroll
    for (int mi = 0; mi < 2; ++mi)
        #pragma unroll
        for (int nj = 0; nj < 4; ++nj) acc[mi][nj] = zero;

    short8 ha[3][2];
    short8 bf[2][4];

    auto fetchA = [&](int kb, int buf) {
        ha[buf][0] = *(const short8*)(A + r0 * 128 + kb * 32 + q * 8);
        ha[buf][1] = *(const short8*)(A + r1 * 128 + kb * 32 + q * 8);
    };
    auto fetchB = [&](int kb, int buf) {
        #pragma unroll
        for (int nj = 0; nj < 4; ++nj)
            bf[buf][nj] = *(const short8*)(smem + kb * 4096 + (ch * 64 + nj * 16 + m16) * 32 + q * 8);
    };

    fetchA(0, 0);
    fetchA(1, 1);
    // stage full B (layout identical to source panels): linear copy
    #pragma unroll
    for (int t = tid; t < 2048; t += 256)
        *(short8*)(smem + t * 8) = *(const short8*)(Bp + t * 8);
    __syncthreads();

    fetchB(0, 0);
    #pragma unroll
    for (int kb = 0; kb < 4; ++kb) {
        if (kb + 2 < 4) fetchA(kb + 2, (kb + 2) % 3);
        if (kb + 1 < 4) fetchB(kb + 1, (kb + 1) & 1);
        const int ca = kb % 3, cb = kb & 1;
        #pragma unroll
        for (int mi = 0; mi < 2; ++mi)
            #pragma unroll
            for (int nj = 0; nj < 4; ++nj)
                acc[mi][nj] = __builtin_amdgcn_mfma_f32_16x16x32_bf16(ha[ca][mi], bf[cb][nj], acc[mi][nj], 0, 0, 0);
    }

    // epilogue -> LDS rows (pitch 136 shorts = 68 uints)
    __syncthreads();
    #pragma unroll
    for (int nj = 0; nj < 4; ++nj) {
        int cl = ch * 64 + nj * 16 + m16;
        float bv = mb1[cl];
        #pragma unroll
        for (int mi = 0; mi < 2; ++mi)
            #pragma unroll
            for (int r = 0; r < 4; ++r)
                smem[(rh * 32 + mi * 16 + q * 4 + r) * 136 + cl] = f2bf(acc[mi][nj][r] + bv);
    }
    __syncthreads();

    // head: wave w processes rows w*16..+16 from LDS
    const unsigned* zl = (const unsigned*)smem;
    int k = lane & 15, seg = lane >> 4;
    float2 gv  = *(const float2*)(g + 2 * lane);
    float2 bev = *(const float2*)(be + 2 * lane);
    for (int rr = 0; rr < 16; ++rr) {
        int lrow = wid * 16 + rr;
        long long grow = rowbase + lrow;
        if (grow >= n) break;
        unsigned u = zl[lrow * 68 + lane];
        float o0, o1; ln_pair(bfl(u), bfh(u), o0, o1);
        float z0 = elu(o0 * gv.x + bev.x);
        float z1 = elu(o1 * gv.y + bev.y);
        float acch = 0.f;
        #pragma unroll
        for (int t = 0; t < 16; ++t) {
            int srcl = seg * 16 + t;
            float zz0 = __shfl(z0, srcl, 64);
            float zz1 = __shfl(z1, srcl, 64);
            int c = seg * 32 + 2 * t;
            acch = fmaf(zz0, mW2[c * 16 + k], acch);
            acch = fmaf(zz1, mW2[(c + 1) * 16 + k], acch);
        }
        acch += __shfl_xor(acch, 32, 64);
        acch += __shfl_xor(acch, 16, 64);
        float hk = acch + mb2[k];
        float mx = hk;
        #pragma unroll
        for (int o = 8; o > 0; o >>= 1) mx = fmaxf(mx, __shfl_xor(mx, o, 64));
        float e = expf(hk - mx);
        float s = e;
        #pragma unroll
        for (int o = 8; o > 0; o >>= 1) s += __shfl_xor(s, o, 64);
        if (lane < 16) out[grow * 16 + k] = e / s;
    }
}

// ---------- CSR pair-gather: lane holds 4 cols (uint2); halves split even/odd edges ----------
__device__ __forceinline__ void gather_row2(
    const unsigned* __restrict__ hw, const int2* __restrict__ csr,
    int beg, int end, int half, int c2, float4& o)
{
    float s0 = 0.f, s1 = 0.f, s2 = 0.f, s3 = 0.f;
    int p = beg;
    for (; p + 15 < end; p += 16) {   // 8 pairs = 16 edges
        uint2 u[8]; float w[8];
        #pragma unroll
        for (int j = 0; j < 8; ++j) {
            int2 e0 = csr[p + 2 * j];
            int2 e1 = csr[p + 2 * j + 1];
            int srcn = half ? e1.x : e0.x;
            w[j] = __int_as_float(half ? e1.y : e0.y);
            u[j] = *(const uint2*)(hw + (long long)srcn * 64 + c2 * 2);
        }
        #pragma unroll
        for (int j = 0; j < 8; ++j) {
            s0 = fmaf(w[j], bfl(u[j].x), s0);
            s1 = fmaf(w[j], bfh(u[j].x), s1);
            s2 = fmaf(w[j], bfl(u[j].y), s2);
            s3 = fmaf(w[j], bfh(u[j].y), s3);
        }
    }
    for (; p + 1 < end; p += 2) {
        int2 e0 = csr[p], e1 = csr[p + 1];
        int srcn = half ? e1.x : e0.x;
        float w = __int_as_float(half ? e1.y : e0.y);
        uint2 u = *(const uint2*)(hw + (long long)srcn * 64 + c2 * 2);
        s0 = fmaf(w, bfl(u.x), s0);
        s1 = fmaf(w, bfh(u.x), s1);
        s2 = fmaf(w, bfl(u.y), s2);
        s3 = fmaf(w, bfh(u.y), s3);
    }
    if (p < end) {   // odd tail: only even half contributes
        int2 e0 = csr[p];
        float w = half ? 0.f : __int_as_float(e0.y);
        uint2 u = *(const uint2*)(hw + (long long)e0.x * 64 + c2 * 2);
        s0 = fmaf(w, bfl(u.x), s0);
        s1 = fmaf(w, bfh(u.x), s1);
        s2 = fmaf(w, bfl(u.y), s2);
        s3 = fmaf(w, bfh(u.y), s3);
    }
    // combine halves (all lanes end with identical per-col sums)
    s0 += __shfl_xor(s0, 32, 64);
    s1 += __shfl_xor(s1, 32, 64);
    s2 += __shfl_xor(s2, 32, 64);
    s3 += __shfl_xor(s3, 32, 64);
    o = make_float4(s0, s1, s2, s3);
}

// layer 1: h = elu(LN(gather + dinv^2*hw + b1)) + LN(proj)
__global__ __launch_bounds__(256) void gfuse1_k(
    const unsigned* __restrict__ hw, const unsigned* __restrict__ proj,
    const int* __restrict__ rowptr, const int2* __restrict__ csr,
    const float* __restrict__ dinv,
    const float* __restrict__ b1, const float* __restrict__ g1, const float* __restrict__ be1,
    const float* __restrict__ rg, const float* __restrict__ rbe,
    unsigned* __restrict__ hout, int n)
{
    int row = blockIdx.x * 4 + (threadIdx.x >> 6);
    if (row >= n) return;
    int lane = threadIdx.x & 63;
    int half = lane >> 5, c2 = lane & 31;
    float4 a;
    gather_row2(hw, csr, rowptr[row], rowptr[row + 1], half, c2, a);
    long long off = (long long)row * 64;
    float di = dinv[row], sl = di * di;
    uint2 us = *(const uint2*)(hw + off + c2 * 2);
    float4 bv  = *(const float4*)(b1 + 4 * c2);
    float4 gv  = *(const float4*)(g1 + 4 * c2);
    float4 bev = *(const float4*)(be1 + 4 * c2);
    float4 rgv = *(const float4*)(rg + 4 * c2);
    float4 rbv = *(const float4*)(rbe + 4 * c2);
    float4 v = make_float4(a.x + sl * bfl(us.x) + bv.x,
                           a.y + sl * bfh(us.x) + bv.y,
                           a.z + sl * bfl(us.y) + bv.z,
                           a.w + sl * bfh(us.y) + bv.w);
    float4 o; ln_quad(v, o);
    float t0 = elu(o.x * gv.x + bev.x);
    float t1 = elu(o.y * gv.y + bev.y);
    float t2 = elu(o.z * gv.z + bev.z);
    float t3 = elu(o.w * gv.w + bev.w);
    uint2 up = *(const uint2*)(proj + off + c2 * 2);
    float4 pv = make_float4(bfl(up.x), bfh(up.x), bfl(up.y), bfh(up.y));
    float4 qo; ln_quad(pv, qo);
    if (!half) {
        uint2 w2;
        w2.x = pack_bf2(t0 + qo.x * rgv.x + rbv.x, t1 + qo.y * rgv.y + rbv.y);
        w2.y = pack_bf2(t2 + qo.z * rgv.z + rbv.z, t3 + qo.w * rgv.w + rbv.w);
        *(uint2*)(hout + off + c2 * 2) = w2;
    }
}

// layer 2: h2 = elu(LN(gather + dinv^2*hw + b2)) + hprev
__global__ __launch_bounds__(256) void gfuse2_k(
    const unsigned* __restrict__ hw, const unsigned* __restrict__ hprev,
    const int* __restrict__ rowptr, const int2* __restrict__ csr,
    const float* __restrict__ dinv,
    const float* __restrict__ b2, const float* __restrict__ g2, const float* __restrict__ be2,
    unsigned* __restrict__ h2, int n)
{
    int row = blockIdx.x * 4 + (threadIdx.x >> 6);
    if (row >= n) return;
    int lane = threadIdx.x & 63;
    int half = lane >> 5, c2 = lane & 31;
    float4 a;
    gather_row2(hw, csr, rowptr[row], rowptr[row + 1], half, c2, a);
    long long off = (long long)row * 64;
    float di = dinv[row], sl = di * di;
    uint2 us = *(const uint2*)(hw + off + c2 * 2);
    float4 bv  = *(const float4*)(b2 + 4 * c2);
    float4 gv  = *(const float4*)(g2 + 4 * c2);
    float4 bev = *(const float4*)(be2 + 4 * c2);
    float4 v = make_float4(a.x + sl * bfl(us.x) + bv.x,
                           a.y + sl * bfh(us.x) + bv.y,
                           a.z + sl * bfl(us.y) + bv.z,
                           a.w + sl * bfh(us.y) + bv.w);
    float4 o; ln_quad(v, o);
    float t0 = elu(o.x * gv.x + bev.x);
    float t1 = elu(o.y * gv.y + bev.y);
    float t2 = elu(o.z * gv.z + bev.z);
    float t3 = elu(o.w * gv.w + bev.w);
    if (!half) {
        uint2 uh = *(const uint2*)(hprev + off + c2 * 2);
        uint2 w2;
        w2.x = pack_bf2(t0 + bfl(uh.x), t1 + bfh(uh.x));
        w2.y = pack_bf2(t2 + bfl(uh.y), t3 + bfh(uh.y));
        *(uint2*)(h2 + off + c2 * 2) = w2;
    }
}

// ---------- launcher ----------
static inline size_t align16(size_t x) { return (x + 15) & ~(size_t)15; }

extern "C" void kernel_launch(void* const* d_in, const int* in_sizes, int n_in,
                              void* d_out, int out_size, void* d_ws, size_t ws_size,
                              hipStream_t stream)
{
    const float* x   = (const float*)d_in[0];
    const int*   ei  = (const int*)d_in[1];
    const float* W1  = (const float*)d_in[2];
    const float* b1  = (const float*)d_in[3];
    const float* g1  = (const float*)d_in[4];
    const float* be1 = (const float*)d_in[5];
    const float* W2  = (const float*)d_in[6];
    const float* b2  = (const float*)d_in[7];
    const float* g2  = (const float*)d_in[8];
    const float* be2 = (const float*)d_in[9];
    const float* rW  = (const float*)d_in[10];
    const float* rb  = (const float*)d_in[11];
    const float* rg  = (const float*)d_in[12];
    const float* rbe = (const float*)d_in[13];
    const float* mW1 = (const float*)d_in[14];
    const float* mb1 = (const float*)d_in[15];
    const float* mg  = (const float*)d_in[16];
    const float* mbe = (const float*)d_in[17];
    const float* mW2 = (const float*)d_in[18];
    const float* mb2 = (const float*)d_in[19];
    float* out = (float*)d_out;

    const int n = in_sizes[0] / 384;
    const int E = in_sizes[1] / 2;
    const int* src = ei;
    const int* dst = ei + E;

    char* w = (char*)d_ws;
    int* deg     = (int*)w;   w += align16((size_t)n * 4);
    int* rowptr  = (int*)w;   w += align16((size_t)(n + 1) * 4);
    int* cursor  = (int*)w;   w += align16((size_t)n * 4);
    float* dinv  = (float*)w; w += align16((size_t)n * 4);
    int* bsum    = (int*)w;   w += align16((size_t)1024 * 4);
    int2* csr    = (int2*)w;  w += align16((size_t)E * 8);
    unsigned short* xb   = (unsigned short*)w; w += align16((size_t)n * 384 * 2);
    unsigned short* hw1  = (unsigned short*)w; w += align16((size_t)n * DH * 2);
    unsigned short* proj = (unsigned short*)w; w += align16((size_t)n * DH * 2);
    unsigned short* hbuf = (unsigned short*)w; w += align16((size_t)n * DH * 2);
    unsigned short* Wp   = (unsigned short*)w; w += align16((size_t)131072 * 2);
    unsigned short* Wp1 = Wp;
    unsigned short* Wpr = Wp + 49152;
    unsigned short* Wp2 = Wp + 98304;
    unsigned short* WpM = Wp + 114688;
    unsigned short* hw2  = hw1;   // free after gfuse1
    unsigned short* h2   = proj;  // free after gfuse1

    int gE = (E + 255) / 256;
    int gN = (n + 255) / 256;
    int nb = (n + 1023) / 1024;
    dim3 gGd((n + 127) / 128, 4);   // dual (matrix x col-half)
    dim3 gGs((n + 127) / 128, 2);   // single
    int gRow4 = (n + 3) / 4;
    int gH = (n + 63) / 64;

    // x -> bf16 (pure streaming, also zeroes deg) + weight repack
    conv_x_k<<<2048, 256, 0, stream>>>(x, xb, (long long)n * 48, deg, n);
    repack_all_k<<<512, 256, 0, stream>>>(W1, rW, W2, mW1, Wp);

    // CSR build
    deg_count_k<<<gE, 256, 0, stream>>>(dst, deg, E);
    scan_part_k<<<nb, 1024, 0, stream>>>(deg, rowptr, bsum, dinv, n);
    scan_top_k<<<1, 64, 0, stream>>>(bsum, rowptr + n, nb);
    scan_add_k<<<gN, 256, 0, stream>>>(bsum, rowptr, cursor, n);
    fill_k<<<gE, 256, 0, stream>>>(src, dst, dinv, cursor, csr, E);

    // layer 1 (dual: hw1 = xb@W1, proj = xb@rW + rb)
    mfma_gemm<384, 2><<<gGd, 256, 0, stream>>>(xb, Wp1, nullptr, Wpr, rb, hw1, proj, n);
    gfuse1_k<<<gRow4, 256, 0, stream>>>((unsigned*)hw1, (unsigned*)proj, rowptr, csr, dinv,
                                        b1, g1, be1, rg, rbe, (unsigned*)hbuf, n);

    // layer 2
    mfma_gemm<128, 1><<<gGs, 256, 0, stream>>>(hbuf, Wp2, nullptr, nullptr, nullptr, hw2, nullptr, n);
    gfuse2_k<<<gRow4, 256, 0, stream>>>((unsigned*)hw2, (unsigned*)hbuf, rowptr, csr, dinv,
                                        b2, g2, be2, (unsigned*)h2, n);

    // fused MLP head + softmax
    gemm_head_k<<<gH, 256, 0, stream>>>(h2, WpM, mb1, mg, mbe, mW2, mb2, out, n);
}

// Round 11
// 439.913 us; speedup vs baseline: 1.1072x; 1.1072x over previous
//
#include <hip/hip_runtime.h>

#define DH 128

typedef __attribute__((ext_vector_type(8))) short short8;
typedef __attribute__((ext_vector_type(4))) float f32x4;

// ---------- helpers ----------
__device__ __forceinline__ float wave_sum(float v) {
    #pragma unroll
    for (int o = 32; o > 0; o >>= 1) v += __shfl_xor(v, o, 64);
    return v;
}

__device__ __forceinline__ void ln_pair(float v0, float v1, float& o0, float& o1) {
    float m = wave_sum(v0 + v1) * (1.f / 128.f);
    float d0 = v0 - m, d1 = v1 - m;
    float var = wave_sum(d0 * d0 + d1 * d1) * (1.f / 128.f);
    float inv = rsqrtf(var + 1e-5f);
    o0 = d0 * inv; o1 = d1 * inv;
}

__device__ __forceinline__ float elu(float x) { return x > 0.f ? x : expm1f(x); }

// fp32 -> bf16 round-to-nearest-even
__device__ __forceinline__ unsigned short f2bf(float f) {
    unsigned u = __float_as_uint(f);
    u += 0x7fffu + ((u >> 16) & 1u);
    return (unsigned short)(u >> 16);
}
__device__ __forceinline__ float bfl(unsigned u) { return __uint_as_float(u << 16); }
__device__ __forceinline__ float bfh(unsigned u) { return __uint_as_float(u & 0xffff0000u); }
__device__ __forceinline__ unsigned pack_bf2(float a, float b) {
    return (unsigned)f2bf(a) | ((unsigned)f2bf(b) << 16);
}
__device__ __forceinline__ short8 cvt8(float4 v0, float4 v1) {
    short8 o;
    o[0] = (short)f2bf(v0.x); o[1] = (short)f2bf(v0.y);
    o[2] = (short)f2bf(v0.z); o[3] = (short)f2bf(v0.w);
    o[4] = (short)f2bf(v1.x); o[5] = (short)f2bf(v1.y);
    o[6] = (short)f2bf(v1.z); o[7] = (short)f2bf(v1.w);
    return o;
}

// ---------- streaming fp32 -> bf16 conversion of x (also zeroes deg) ----------
__global__ __launch_bounds__(256) void conv_x_k(const float* __restrict__ x,
                                                unsigned short* __restrict__ xb,
                                                long long n8, int* __restrict__ deg, int n)
{
    long long i = (long long)blockIdx.x * 256 + threadIdx.x;
    if (i < n) deg[i] = 0;
    long long stride = (long long)gridDim.x * 256;
    for (; i < n8; i += stride) {
        float4 v0 = *(const float4*)(x + i * 8);
        float4 v1 = *(const float4*)(x + i * 8 + 4);
        *(short8*)(xb + i * 8) = cvt8(v0, v1);
    }
}

// ---------- utility kernels ----------
__global__ void deg_count_k(const int* __restrict__ dst, int* __restrict__ deg, int E) {
    int e = blockIdx.x * 256 + threadIdx.x;
    if (e < E) atomicAdd(&deg[dst[e]], 1);
}

// ---------- parallel exclusive scan (3 kernels); also emits dinv ----------
__global__ __launch_bounds__(1024) void scan_part_k(const int* __restrict__ deg,
                                                    int* __restrict__ rowptr,
                                                    int* __restrict__ bsum,
                                                    float* __restrict__ dinv, int n)
{
    __shared__ int wsum[16];
    const int tid = threadIdx.x, lane = tid & 63, wid = tid >> 6;
    int i = blockIdx.x * 1024 + tid;
    int v = (i < n) ? deg[i] : 0;
    if (i < n) dinv[i] = rsqrtf((float)(v + 1));  // +1 self-loop
    int s = v;
    #pragma unroll
    for (int o = 1; o < 64; o <<= 1) {
        int t = __shfl_up(s, o, 64);
        if (lane >= o) s += t;
    }
    if (lane == 63) wsum[wid] = s;
    __syncthreads();
    if (tid < 16) {
        int ws = wsum[tid];
        #pragma unroll
        for (int o = 1; o < 16; o <<= 1) {
            int t = __shfl_up(ws, o, 64);
            if (tid >= o) ws += t;
        }
        wsum[tid] = ws;
    }
    __syncthreads();
    int excl = (wid ? wsum[wid - 1] : 0) + s - v;
    if (i < n) rowptr[i] = excl;
    if (tid == 0) bsum[blockIdx.x] = wsum[15];
}

__global__ void scan_top_k(int* __restrict__ bsum, int* __restrict__ rowptr_n, int nb) {
    int lane = threadIdx.x;  // blockDim = 64
    int carry = 0;
    for (int base = 0; base < nb; base += 64) {
        int i = base + lane;
        int v = (i < nb) ? bsum[i] : 0;
        int s = v;
        #pragma unroll
        for (int o = 1; o < 64; o <<= 1) {
            int t = __shfl_up(s, o, 64);
            if (lane >= o) s += t;
        }
        if (i < nb) bsum[i] = carry + s - v;
        carry += __shfl(s, 63, 64);
    }
    if (lane == 0) *rowptr_n = carry;
}

__global__ void scan_add_k(const int* __restrict__ bsum, int* __restrict__ rowptr,
                           int* __restrict__ cursor, int n)
{
    int i = blockIdx.x * 256 + threadIdx.x;
    if (i < n) {
        int v = rowptr[i] + bsum[i >> 10];
        rowptr[i] = v;
        cursor[i] = v;
    }
}

__global__ void fill_k(const int* __restrict__ src, const int* __restrict__ dst,
                       const float* __restrict__ dinv, int* __restrict__ cursor,
                       int2* __restrict__ csr, int E)
{
    int e = blockIdx.x * 256 + threadIdx.x;
    if (e < E) {
        int s = src[e], d = dst[e];
        float w = dinv[s] * dinv[d];
        int p = atomicAdd(&cursor[d], 1);
        csr[p] = make_int2(s, __float_as_int(w));
    }
}

// repack all four W's fp32 -> bf16 fragment panels [kb][n][32] into one buffer
__global__ void repack_all_k(const float* __restrict__ W1, const float* __restrict__ rW,
                             const float* __restrict__ W2, const float* __restrict__ mW1,
                             unsigned short* __restrict__ Wp)
{
    int idx = blockIdx.x * 256 + threadIdx.x;
    if (idx >= 131072) return;
    const float* W; int base;
    if (idx < 49152)       { W = W1;  base = 0; }
    else if (idx < 98304)  { W = rW;  base = 49152; }
    else if (idx < 114688) { W = W2;  base = 98304; }
    else                   { W = mW1; base = 114688; }
    int l = idx - base;
    int kb = l >> 12, rem = l & 4095;
    int nn = rem >> 5, ki = rem & 31;
    Wp[idx] = f2bf(W[(kb * 32 + ki) * DH + nn]);
}

// ---------- MFMA GEMM: B panel resident in LDS, barrier-free K-loop ----------
template<int K, int NMAT>
__global__ __launch_bounds__(256, 3) void mfma_gemm(
    const unsigned short* __restrict__ A,
    const unsigned short* __restrict__ Bp1, const float* __restrict__ ba,
    const unsigned short* __restrict__ Bp2, const float* __restrict__ bb,
    unsigned short* __restrict__ outa, unsigned short* __restrict__ outb, int n)
{
    constexpr int NKB = K / 32;
    constexpr int SB   = NKB * 64 * 32;
    constexpr int SEP  = 128 * 72;
    constexpr int SMEM = SB > SEP ? SB : SEP;
    __shared__ __align__(16) unsigned short smem[SMEM];

    const int tid = threadIdx.x;
    const int wid = tid >> 6, lane = tid & 63;
    const int m16 = lane & 15, q = lane >> 4;
    const int mat = (NMAT == 2) ? (int)(blockIdx.y >> 1) : 0;
    const int c0  = (blockIdx.y & 1) * 64;
    const unsigned short* Bp = mat ? Bp2 : Bp1;
    unsigned short* outp = mat ? outb : outa;
    const float* bias = mat ? bb : ba;
    const long long rowbase = (long long)blockIdx.x * 128;

    long long r0 = rowbase + wid * 32 + m16;       if (r0 > (long long)n - 1) r0 = n - 1;
    long long r1 = rowbase + wid * 32 + 16 + m16;  if (r1 > (long long)n - 1) r1 = n - 1;

    f32x4 acc[2][4];
    const f32x4 zero = {0.f, 0.f, 0.f, 0.f};
    #pragma unroll
    for (int mi = 0; mi < 2; ++mi)
        #pragma unroll
        for (int nj = 0; nj < 4; ++nj) acc[mi][nj] = zero;

    short8 ha[3][2];
    short8 bf[2][4];

    auto fetchA = [&](int kb, int buf) {
        ha[buf][0] = *(const short8*)(A + r0 * K + kb * 32 + q * 8);
        ha[buf][1] = *(const short8*)(A + r1 * K + kb * 32 + q * 8);
    };
    auto fetchB = [&](int kb, int buf) {
        #pragma unroll
        for (int nj = 0; nj < 4; ++nj)
            bf[buf][nj] = *(const short8*)(smem + kb * 2048 + (nj * 16 + m16) * 32 + q * 8);
    };

    fetchA(0, 0);
    if constexpr (NKB > 1) fetchA(1, 1);

    #pragma unroll
    for (int t = tid; t < K * 8; t += 256) {
        int k8 = t & 3, cl = (t >> 2) & 63, kb = t >> 8;
        *(short8*)(smem + kb * 2048 + cl * 32 + k8 * 8) =
            *(const short8*)(Bp + (long long)kb * 4096 + (c0 + cl) * 32 + k8 * 8);
    }
    __syncthreads();

    fetchB(0, 0);
    #pragma unroll
    for (int kb = 0; kb < NKB; ++kb) {
        if (kb + 2 < NKB) fetchA(kb + 2, (kb + 2) % 3);
        if (kb + 1 < NKB) fetchB(kb + 1, (kb + 1) & 1);
        const int ca = kb % 3, cb = kb & 1;
        #pragma unroll
        for (int mi = 0; mi < 2; ++mi)
            #pragma unroll
            for (int nj = 0; nj < 4; ++nj)
                acc[mi][nj] = __builtin_amdgcn_mfma_f32_16x16x32_bf16(ha[ca][mi], bf[cb][nj], acc[mi][nj], 0, 0, 0);
    }

    __syncthreads();
    #pragma unroll
    for (int nj = 0; nj < 4; ++nj) {
        int cl = nj * 16 + m16;
        float bv = bias ? bias[c0 + cl] : 0.f;
        #pragma unroll
        for (int mi = 0; mi < 2; ++mi)
            #pragma unroll
            for (int r = 0; r < 4; ++r)
                smem[(wid * 32 + mi * 16 + q * 4 + r) * 72 + cl] = f2bf(acc[mi][nj][r] + bv);
    }
    __syncthreads();
    #pragma unroll
    for (int h = 0; h < 4; ++h) {
        int idx = tid + h * 256;
        int row = idx >> 3, c8 = idx & 7;
        long long grow = rowbase + row;
        if (grow < n)
            *(short8*)(outp + grow * DH + c0 + c8 * 8) = *(const short8*)(smem + row * 72 + c8 * 8);
    }
}

// ---------- fused GEMM (K=128, full 128 cols) + LN/ELU + mW2 + softmax ----------
__global__ __launch_bounds__(256, 3) void gemm_head_k(
    const unsigned short* __restrict__ A, const unsigned short* __restrict__ Bp,
    const float* __restrict__ mb1,
    const float* __restrict__ g, const float* __restrict__ be,
    const float* __restrict__ mW2, const float* __restrict__ mb2,
    float* __restrict__ out, int n)
{
    __shared__ __align__(16) unsigned short smem[16384];
    const int tid = threadIdx.x;
    const int wid = tid >> 6, lane = tid & 63;
    const int m16 = lane & 15, q = lane >> 4;
    const int rh = wid >> 1, ch = wid & 1;
    const long long rowbase = (long long)blockIdx.x * 64;

    long long r0 = rowbase + rh * 32 + m16;       if (r0 > (long long)n - 1) r0 = n - 1;
    long long r1 = rowbase + rh * 32 + 16 + m16;  if (r1 > (long long)n - 1) r1 = n - 1;

    f32x4 acc[2][4];
    const f32x4 zero = {0.f, 0.f, 0.f, 0.f};
    #pragma unroll
    for (int mi = 0; mi < 2; ++mi)
        #pragma unroll
        for (int nj = 0; nj < 4; ++nj) acc[mi][nj] = zero;

    short8 ha[3][2];
    short8 bf[2][4];

    auto fetchA = [&](int kb, int buf) {
        ha[buf][0] = *(const short8*)(A + r0 * 128 + kb * 32 + q * 8);
        ha[buf][1] = *(const short8*)(A + r1 * 128 + kb * 32 + q * 8);
    };
    auto fetchB = [&](int kb, int buf) {
        #pragma unroll
        for (int nj = 0; nj < 4; ++nj)
            bf[buf][nj] = *(const short8*)(smem + kb * 4096 + (ch * 64 + nj * 16 + m16) * 32 + q * 8);
    };

    fetchA(0, 0);
    fetchA(1, 1);
    #pragma unroll
    for (int t = tid; t < 2048; t += 256)
        *(short8*)(smem + t * 8) = *(const short8*)(Bp + t * 8);
    __syncthreads();

    fetchB(0, 0);
    #pragma unroll
    for (int kb = 0; kb < 4; ++kb) {
        if (kb + 2 < 4) fetchA(kb + 2, (kb + 2) % 3);
        if (kb + 1 < 4) fetchB(kb + 1, (kb + 1) & 1);
        const int ca = kb % 3, cb = kb & 1;
        #pragma unroll
        for (int mi = 0; mi < 2; ++mi)
            #pragma unroll
            for (int nj = 0; nj < 4; ++nj)
                acc[mi][nj] = __builtin_amdgcn_mfma_f32_16x16x32_bf16(ha[ca][mi], bf[cb][nj], acc[mi][nj], 0, 0, 0);
    }

    // epilogue -> LDS rows (pitch 136 shorts = 68 uints)
    __syncthreads();
    #pragma unroll
    for (int nj = 0; nj < 4; ++nj) {
        int cl = ch * 64 + nj * 16 + m16;
        float bv = mb1[cl];
        #pragma unroll
        for (int mi = 0; mi < 2; ++mi)
            #pragma unroll
            for (int r = 0; r < 4; ++r)
                smem[(rh * 32 + mi * 16 + q * 4 + r) * 136 + cl] = f2bf(acc[mi][nj][r] + bv);
    }
    __syncthreads();

    // head: wave w processes rows w*16..+16 from LDS
    const unsigned* zl = (const unsigned*)smem;
    int k = lane & 15, seg = lane >> 4;
    float2 gv  = *(const float2*)(g + 2 * lane);
    float2 bev = *(const float2*)(be + 2 * lane);
    for (int rr = 0; rr < 16; ++rr) {
        int lrow = wid * 16 + rr;
        long long grow = rowbase + lrow;
        if (grow >= n) break;
        unsigned u = zl[lrow * 68 + lane];
        float o0, o1; ln_pair(bfl(u), bfh(u), o0, o1);
        float z0 = elu(o0 * gv.x + bev.x);
        float z1 = elu(o1 * gv.y + bev.y);
        float acch = 0.f;
        #pragma unroll
        for (int t = 0; t < 16; ++t) {
            int srcl = seg * 16 + t;
            float zz0 = __shfl(z0, srcl, 64);
            float zz1 = __shfl(z1, srcl, 64);
            int c = seg * 32 + 2 * t;
            acch = fmaf(zz0, mW2[c * 16 + k], acch);
            acch = fmaf(zz1, mW2[(c + 1) * 16 + k], acch);
        }
        acch += __shfl_xor(acch, 32, 64);
        acch += __shfl_xor(acch, 16, 64);
        float hk = acch + mb2[k];
        float mx = hk;
        #pragma unroll
        for (int o = 8; o > 0; o >>= 1) mx = fmaxf(mx, __shfl_xor(mx, o, 64));
        float e = expf(hk - mx);
        float s = e;
        #pragma unroll
        for (int o = 8; o > 0; o >>= 1) s += __shfl_xor(s, o, 64);
        if (lane < 16) out[grow * 16 + k] = e / s;
    }
}

// ---------- CSR gather (bf16 rows), one wave per row, 8 loads in flight ----------
__device__ __forceinline__ void gather_row(
    const unsigned* __restrict__ hw, const int2* __restrict__ csr,
    int beg, int end, int lane, float& o0, float& o1)
{
    float a0 = 0.f, a1 = 0.f, b0 = 0.f, b1 = 0.f;
    float c0 = 0.f, c1 = 0.f, d0 = 0.f, d1 = 0.f;
    int p = beg;
    for (; p + 7 < end; p += 8) {
        int2 e0 = csr[p],     e1 = csr[p + 1], e2 = csr[p + 2], e3 = csr[p + 3];
        int2 e4 = csr[p + 4], e5 = csr[p + 5], e6 = csr[p + 6], e7 = csr[p + 7];
        unsigned u0 = hw[(long long)e0.x * 64 + lane];
        unsigned u1 = hw[(long long)e1.x * 64 + lane];
        unsigned u2 = hw[(long long)e2.x * 64 + lane];
        unsigned u3 = hw[(long long)e3.x * 64 + lane];
        unsigned u4 = hw[(long long)e4.x * 64 + lane];
        unsigned u5 = hw[(long long)e5.x * 64 + lane];
        unsigned u6 = hw[(long long)e6.x * 64 + lane];
        unsigned u7 = hw[(long long)e7.x * 64 + lane];
        float w0 = __int_as_float(e0.y), w1 = __int_as_float(e1.y);
        float w2 = __int_as_float(e2.y), w3 = __int_as_float(e3.y);
        float w4 = __int_as_float(e4.y), w5 = __int_as_float(e5.y);
        float w6 = __int_as_float(e6.y), w7 = __int_as_float(e7.y);
        a0 = fmaf(w0, bfl(u0), a0);  a1 = fmaf(w0, bfh(u0), a1);
        b0 = fmaf(w1, bfl(u1), b0);  b1 = fmaf(w1, bfh(u1), b1);
        c0 = fmaf(w2, bfl(u2), c0);  c1 = fmaf(w2, bfh(u2), c1);
        d0 = fmaf(w3, bfl(u3), d0);  d1 = fmaf(w3, bfh(u3), d1);
        a0 = fmaf(w4, bfl(u4), a0);  a1 = fmaf(w4, bfh(u4), a1);
        b0 = fmaf(w5, bfl(u5), b0);  b1 = fmaf(w5, bfh(u5), b1);
        c0 = fmaf(w6, bfl(u6), c0);  c1 = fmaf(w6, bfh(u6), c1);
        d0 = fmaf(w7, bfl(u7), d0);  d1 = fmaf(w7, bfh(u7), d1);
    }
    for (; p + 3 < end; p += 4) {
        int2 e0 = csr[p], e1 = csr[p + 1], e2 = csr[p + 2], e3 = csr[p + 3];
        unsigned u0 = hw[(long long)e0.x * 64 + lane];
        unsigned u1 = hw[(long long)e1.x * 64 + lane];
        unsigned u2 = hw[(long long)e2.x * 64 + lane];
        unsigned u3 = hw[(long long)e3.x * 64 + lane];
        float w0 = __int_as_float(e0.y), w1 = __int_as_float(e1.y);
        float w2 = __int_as_float(e2.y), w3 = __int_as_float(e3.y);
        a0 = fmaf(w0, bfl(u0), a0);  a1 = fmaf(w0, bfh(u0), a1);
        b0 = fmaf(w1, bfl(u1), b0);  b1 = fmaf(w1, bfh(u1), b1);
        c0 = fmaf(w2, bfl(u2), c0);  c1 = fmaf(w2, bfh(u2), c1);
        d0 = fmaf(w3, bfl(u3), d0);  d1 = fmaf(w3, bfh(u3), d1);
    }
    for (; p < end; ++p) {
        int2 e0 = csr[p];
        unsigned u0 = hw[(long long)e0.x * 64 + lane];
        float w0 = __int_as_float(e0.y);
        a0 = fmaf(w0, bfl(u0), a0);
        a1 = fmaf(w0, bfh(u0), a1);
    }
    o0 = (a0 + b0) + (c0 + d0);
    o1 = (a1 + b1) + (c1 + d1);
}

// layer 1: h = elu(LN(gather + dinv^2*hw + b1)) + LN(proj)
__global__ __launch_bounds__(256) void gfuse1_k(
    const unsigned* __restrict__ hw, const unsigned* __restrict__ proj,
    const int* __restrict__ rowptr, const int2* __restrict__ csr,
    const float* __restrict__ dinv,
    const float* __restrict__ b1, const float* __restrict__ g1, const float* __restrict__ be1,
    const float* __restrict__ rg, const float* __restrict__ rbe,
    unsigned* __restrict__ hout, int n)
{
    int row = blockIdx.x * 4 + (threadIdx.x >> 6);
    if (row >= n) return;
    int lane = threadIdx.x & 63;
    float a0, a1;
    gather_row(hw, csr, rowptr[row], rowptr[row + 1], lane, a0, a1);
    long long off = (long long)row * 64;
    float di = dinv[row], sl = di * di;
    unsigned us = hw[off + lane];
    float2 bv  = *(const float2*)(b1 + 2 * lane);
    float2 gv  = *(const float2*)(g1 + 2 * lane);
    float2 bev = *(const float2*)(be1 + 2 * lane);
    float2 rgv = *(const float2*)(rg + 2 * lane);
    float2 rbv = *(const float2*)(rbe + 2 * lane);
    float v0 = a0 + sl * bfl(us) + bv.x;
    float v1 = a1 + sl * bfh(us) + bv.y;
    float o0, o1; ln_pair(v0, v1, o0, o1);
    float t0 = elu(o0 * gv.x + bev.x);
    float t1 = elu(o1 * gv.y + bev.y);
    unsigned up = proj[off + lane];
    float q0, q1; ln_pair(bfl(up), bfh(up), q0, q1);
    hout[off + lane] = pack_bf2(t0 + q0 * rgv.x + rbv.x, t1 + q1 * rgv.y + rbv.y);
}

// layer 2: h2 = elu(LN(gather + dinv^2*hw + b2)) + hprev
__global__ __launch_bounds__(256) void gfuse2_k(
    const unsigned* __restrict__ hw, const unsigned* __restrict__ hprev,
    const int* __restrict__ rowptr, const int2* __restrict__ csr,
    const float* __restrict__ dinv,
    const float* __restrict__ b2, const float* __restrict__ g2, const float* __restrict__ be2,
    unsigned* __restrict__ h2, int n)
{
    int row = blockIdx.x * 4 + (threadIdx.x >> 6);
    if (row >= n) return;
    int lane = threadIdx.x & 63;
    float a0, a1;
    gather_row(hw, csr, rowptr[row], rowptr[row + 1], lane, a0, a1);
    long long off = (long long)row * 64;
    float di = dinv[row], sl = di * di;
    unsigned us = hw[off + lane];
    float2 bv  = *(const float2*)(b2 + 2 * lane);
    float2 gv  = *(const float2*)(g2 + 2 * lane);
    float2 bev = *(const float2*)(be2 + 2 * lane);
    float v0 = a0 + sl * bfl(us) + bv.x;
    float v1 = a1 + sl * bfh(us) + bv.y;
    float o0, o1; ln_pair(v0, v1, o0, o1);
    float t0 = elu(o0 * gv.x + bev.x);
    float t1 = elu(o1 * gv.y + bev.y);
    unsigned uh = hprev[off + lane];
    h2[off + lane] = pack_bf2(t0 + bfl(uh), t1 + bfh(uh));
}

// ---------- launcher ----------
static inline size_t align16(size_t x) { return (x + 15) & ~(size_t)15; }

extern "C" void kernel_launch(void* const* d_in, const int* in_sizes, int n_in,
                              void* d_out, int out_size, void* d_ws, size_t ws_size,
                              hipStream_t stream)
{
    const float* x   = (const float*)d_in[0];
    const int*   ei  = (const int*)d_in[1];
    const float* W1  = (const float*)d_in[2];
    const float* b1  = (const float*)d_in[3];
    const float* g1  = (const float*)d_in[4];
    const float* be1 = (const float*)d_in[5];
    const float* W2  = (const float*)d_in[6];
    const float* b2  = (const float*)d_in[7];
    const float* g2  = (const float*)d_in[8];
    const float* be2 = (const float*)d_in[9];
    const float* rW  = (const float*)d_in[10];
    const float* rb  = (const float*)d_in[11];
    const float* rg  = (const float*)d_in[12];
    const float* rbe = (const float*)d_in[13];
    const float* mW1 = (const float*)d_in[14];
    const float* mb1 = (const float*)d_in[15];
    const float* mg  = (const float*)d_in[16];
    const float* mbe = (const float*)d_in[17];
    const float* mW2 = (const float*)d_in[18];
    const float* mb2 = (const float*)d_in[19];
    float* out = (float*)d_out;

    const int n = in_sizes[0] / 384;
    const int E = in_sizes[1] / 2;
    const int* src = ei;
    const int* dst = ei + E;

    char* w = (char*)d_ws;
    int* deg     = (int*)w;   w += align16((size_t)n * 4);
    int* rowptr  = (int*)w;   w += align16((size_t)(n + 1) * 4);
    int* cursor  = (int*)w;   w += align16((size_t)n * 4);
    float* dinv  = (float*)w; w += align16((size_t)n * 4);
    int* bsum    = (int*)w;   w += align16((size_t)1024 * 4);
    int2* csr    = (int2*)w;  w += align16((size_t)E * 8);
    unsigned short* xb   = (unsigned short*)w; w += align16((size_t)n * 384 * 2);
    unsigned short* hw1  = (unsigned short*)w; w += align16((size_t)n * DH * 2);
    unsigned short* proj = (unsigned short*)w; w += align16((size_t)n * DH * 2);
    unsigned short* hbuf = (unsigned short*)w; w += align16((size_t)n * DH * 2);
    unsigned short* Wp   = (unsigned short*)w; w += align16((size_t)131072 * 2);
    unsigned short* Wp1 = Wp;
    unsigned short* Wpr = Wp + 49152;
    unsigned short* Wp2 = Wp + 98304;
    unsigned short* WpM = Wp + 114688;
    unsigned short* hw2  = hw1;   // free after gfuse1
    unsigned short* h2   = proj;  // free after gfuse1

    int gE = (E + 255) / 256;
    int gN = (n + 255) / 256;
    int nb = (n + 1023) / 1024;
    dim3 gGd((n + 127) / 128, 4);   // dual (matrix x col-half)
    dim3 gGs((n + 127) / 128, 2);   // single
    int gRow4 = (n + 3) / 4;
    int gH = (n + 63) / 64;

    // x -> bf16 (pure streaming, also zeroes deg) + weight repack
    conv_x_k<<<2048, 256, 0, stream>>>(x, xb, (long long)n * 48, deg, n);
    repack_all_k<<<512, 256, 0, stream>>>(W1, rW, W2, mW1, Wp);

    // CSR build
    deg_count_k<<<gE, 256, 0, stream>>>(dst, deg, E);
    scan_part_k<<<nb, 1024, 0, stream>>>(deg, rowptr, bsum, dinv, n);
    scan_top_k<<<1, 64, 0, stream>>>(bsum, rowptr + n, nb);
    scan_add_k<<<gN, 256, 0, stream>>>(bsum, rowptr, cursor, n);
    fill_k<<<gE, 256, 0, stream>>>(src, dst, dinv, cursor, csr, E);

    // layer 1 (dual: hw1 = xb@W1, proj = xb@rW + rb)
    mfma_gemm<384, 2><<<gGd, 256, 0, stream>>>(xb, Wp1, nullptr, Wpr, rb, hw1, proj, n);
    gfuse1_k<<<gRow4, 256, 0, stream>>>((unsigned*)hw1, (unsigned*)proj, rowptr, csr, dinv,
                                        b1, g1, be1, rg, rbe, (unsigned*)hbuf, n);

    // layer 2
    mfma_gemm<128, 1><<<gGs, 256, 0, stream>>>(hbuf, Wp2, nullptr, nullptr, nullptr, hw2, nullptr, n);
    gfuse2_k<<<gRow4, 256, 0, stream>>>((unsigned*)hw2, (unsigned*)hbuf, rowptr, csr, dinv,
                                        b2, g2, be2, (unsigned*)h2, n);

    // fused MLP head + softmax
    gemm_head_k<<<gH, 256, 0, stream>>>(h2, WpM, mb1, mg, mbe, mW2, mb2, out, n);
}

// Round 12
// 437.141 us; speedup vs baseline: 1.1142x; 1.0063x over previous
//
#include <hip/hip_runtime.h>

#define DH 128

typedef __attribute__((ext_vector_type(8))) short short8;
typedef __attribute__((ext_vector_type(4))) float f32x4;

// ---------- helpers ----------
__device__ __forceinline__ float wave_sum(float v) {
    #pragma unroll
    for (int o = 32; o > 0; o >>= 1) v += __shfl_xor(v, o, 64);
    return v;
}

__device__ __forceinline__ void ln_pair(float v0, float v1, float& o0, float& o1) {
    float m = wave_sum(v0 + v1) * (1.f / 128.f);
    float d0 = v0 - m, d1 = v1 - m;
    float var = wave_sum(d0 * d0 + d1 * d1) * (1.f / 128.f);
    float inv = rsqrtf(var + 1e-5f);
    o0 = d0 * inv; o1 = d1 * inv;
}

__device__ __forceinline__ float elu(float x) { return x > 0.f ? x : expm1f(x); }

// fp32 -> bf16 round-to-nearest-even
__device__ __forceinline__ unsigned short f2bf(float f) {
    unsigned u = __float_as_uint(f);
    u += 0x7fffu + ((u >> 16) & 1u);
    return (unsigned short)(u >> 16);
}
__device__ __forceinline__ float bfl(unsigned u) { return __uint_as_float(u << 16); }
__device__ __forceinline__ float bfh(unsigned u) { return __uint_as_float(u & 0xffff0000u); }
__device__ __forceinline__ unsigned pack_bf2(float a, float b) {
    return (unsigned)f2bf(a) | ((unsigned)f2bf(b) << 16);
}
__device__ __forceinline__ short8 cvt8(float4 v0, float4 v1) {
    short8 o;
    o[0] = (short)f2bf(v0.x); o[1] = (short)f2bf(v0.y);
    o[2] = (short)f2bf(v0.z); o[3] = (short)f2bf(v0.w);
    o[4] = (short)f2bf(v1.x); o[5] = (short)f2bf(v1.y);
    o[6] = (short)f2bf(v1.z); o[7] = (short)f2bf(v1.w);
    return o;
}

// ---------- streaming fp32 -> bf16 conversion of x (also zeroes deg) ----------
__global__ __launch_bounds__(256) void conv_x_k(const float* __restrict__ x,
                                                unsigned short* __restrict__ xb,
                                                long long n8, int* __restrict__ deg, int n)
{
    long long i = (long long)blockIdx.x * 256 + threadIdx.x;
    if (i < n) deg[i] = 0;
    long long stride = (long long)gridDim.x * 256;
    for (; i < n8; i += stride) {
        float4 v0 = *(const float4*)(x + i * 8);
        float4 v1 = *(const float4*)(x + i * 8 + 4);
        *(short8*)(xb + i * 8) = cvt8(v0, v1);
    }
}

// ---------- utility kernels ----------
__global__ void deg_count_k(const int* __restrict__ dst, int* __restrict__ deg, int E) {
    int e = blockIdx.x * 256 + threadIdx.x;
    if (e < E) atomicAdd(&deg[dst[e]], 1);
}

// ---------- parallel exclusive scan (3 kernels); also emits dinv ----------
__global__ __launch_bounds__(1024) void scan_part_k(const int* __restrict__ deg,
                                                    int* __restrict__ rowptr,
                                                    int* __restrict__ bsum,
                                                    float* __restrict__ dinv, int n)
{
    __shared__ int wsum[16];
    const int tid = threadIdx.x, lane = tid & 63, wid = tid >> 6;
    int i = blockIdx.x * 1024 + tid;
    int v = (i < n) ? deg[i] : 0;
    if (i < n) dinv[i] = rsqrtf((float)(v + 1));  // +1 self-loop
    int s = v;
    #pragma unroll
    for (int o = 1; o < 64; o <<= 1) {
        int t = __shfl_up(s, o, 64);
        if (lane >= o) s += t;
    }
    if (lane == 63) wsum[wid] = s;
    __syncthreads();
    if (tid < 16) {
        int ws = wsum[tid];
        #pragma unroll
        for (int o = 1; o < 16; o <<= 1) {
            int t = __shfl_up(ws, o, 64);
            if (tid >= o) ws += t;
        }
        wsum[tid] = ws;
    }
    __syncthreads();
    int excl = (wid ? wsum[wid - 1] : 0) + s - v;
    if (i < n) rowptr[i] = excl;
    if (tid == 0) bsum[blockIdx.x] = wsum[15];
}

__global__ void scan_top_k(int* __restrict__ bsum, int* __restrict__ rowptr_n, int nb) {
    int lane = threadIdx.x;  // blockDim = 64
    int carry = 0;
    for (int base = 0; base < nb; base += 64) {
        int i = base + lane;
        int v = (i < nb) ? bsum[i] : 0;
        int s = v;
        #pragma unroll
        for (int o = 1; o < 64; o <<= 1) {
            int t = __shfl_up(s, o, 64);
            if (lane >= o) s += t;
        }
        if (i < nb) bsum[i] = carry + s - v;
        carry += __shfl(s, 63, 64);
    }
    if (lane == 0) *rowptr_n = carry;
}

__global__ void scan_add_k(const int* __restrict__ bsum, int* __restrict__ rowptr,
                           int* __restrict__ cursor, int n)
{
    int i = blockIdx.x * 256 + threadIdx.x;
    if (i < n) {
        int v = rowptr[i] + bsum[i >> 10];
        rowptr[i] = v;
        cursor[i] = v;
    }
}

__global__ void fill_k(const int* __restrict__ src, const int* __restrict__ dst,
                       const float* __restrict__ dinv, int* __restrict__ cursor,
                       int2* __restrict__ csr, int E)
{
    int e = blockIdx.x * 256 + threadIdx.x;
    if (e < E) {
        int s = src[e], d = dst[e];
        float w = dinv[s] * dinv[d];
        int p = atomicAdd(&cursor[d], 1);
        csr[p] = make_int2(s, __float_as_int(w));
    }
}

// repack all four W's fp32 -> bf16 fragment panels [kb][n][32] into one buffer
__global__ void repack_all_k(const float* __restrict__ W1, const float* __restrict__ rW,
                             const float* __restrict__ W2, const float* __restrict__ mW1,
                             unsigned short* __restrict__ Wp)
{
    int idx = blockIdx.x * 256 + threadIdx.x;
    if (idx >= 131072) return;
    const float* W; int base;
    if (idx < 49152)       { W = W1;  base = 0; }
    else if (idx < 98304)  { W = rW;  base = 49152; }
    else if (idx < 114688) { W = W2;  base = 98304; }
    else                   { W = mW1; base = 114688; }
    int l = idx - base;
    int kb = l >> 12, rem = l & 4095;
    int nn = rem >> 5, ki = rem & 31;
    Wp[idx] = f2bf(W[(kb * 32 + ki) * DH + nn]);
}

// ---------- MFMA GEMM: B panel resident in LDS, barrier-free K-loop ----------
template<int K, int NMAT>
__global__ __launch_bounds__(256, 3) void mfma_gemm(
    const unsigned short* __restrict__ A,
    const unsigned short* __restrict__ Bp1, const float* __restrict__ ba,
    const unsigned short* __restrict__ Bp2, const float* __restrict__ bb,
    unsigned short* __restrict__ outa, unsigned short* __restrict__ outb, int n)
{
    constexpr int NKB = K / 32;
    constexpr int SB   = NKB * 64 * 32;
    constexpr int SEP  = 128 * 72;
    constexpr int SMEM = SB > SEP ? SB : SEP;
    __shared__ __align__(16) unsigned short smem[SMEM];

    const int tid = threadIdx.x;
    const int wid = tid >> 6, lane = tid & 63;
    const int m16 = lane & 15, q = lane >> 4;
    const int mat = (NMAT == 2) ? (int)(blockIdx.y >> 1) : 0;
    const int c0  = (blockIdx.y & 1) * 64;
    const unsigned short* Bp = mat ? Bp2 : Bp1;
    unsigned short* outp = mat ? outb : outa;
    const float* bias = mat ? bb : ba;
    const long long rowbase = (long long)blockIdx.x * 128;

    long long r0 = rowbase + wid * 32 + m16;       if (r0 > (long long)n - 1) r0 = n - 1;
    long long r1 = rowbase + wid * 32 + 16 + m16;  if (r1 > (long long)n - 1) r1 = n - 1;

    f32x4 acc[2][4];
    const f32x4 zero = {0.f, 0.f, 0.f, 0.f};
    #pragma unroll
    for (int mi = 0; mi < 2; ++mi)
        #pragma unroll
        for (int nj = 0; nj < 4; ++nj) acc[mi][nj] = zero;

    short8 ha[3][2];
    short8 bf[2][4];

    auto fetchA = [&](int kb, int buf) {
        ha[buf][0] = *(const short8*)(A + r0 * K + kb * 32 + q * 8);
        ha[buf][1] = *(const short8*)(A + r1 * K + kb * 32 + q * 8);
    };
    auto fetchB = [&](int kb, int buf) {
        #pragma unroll
        for (int nj = 0; nj < 4; ++nj)
            bf[buf][nj] = *(const short8*)(smem + kb * 2048 + (nj * 16 + m16) * 32 + q * 8);
    };

    fetchA(0, 0);
    if constexpr (NKB > 1) fetchA(1, 1);

    #pragma unroll
    for (int t = tid; t < K * 8; t += 256) {
        int k8 = t & 3, cl = (t >> 2) & 63, kb = t >> 8;
        *(short8*)(smem + kb * 2048 + cl * 32 + k8 * 8) =
            *(const short8*)(Bp + (long long)kb * 4096 + (c0 + cl) * 32 + k8 * 8);
    }
    __syncthreads();

    fetchB(0, 0);
    #pragma unroll
    for (int kb = 0; kb < NKB; ++kb) {
        if (kb + 2 < NKB) fetchA(kb + 2, (kb + 2) % 3);
        if (kb + 1 < NKB) fetchB(kb + 1, (kb + 1) & 1);
        const int ca = kb % 3, cb = kb & 1;
        #pragma unroll
        for (int mi = 0; mi < 2; ++mi)
            #pragma unroll
            for (int nj = 0; nj < 4; ++nj)
                acc[mi][nj] = __builtin_amdgcn_mfma_f32_16x16x32_bf16(ha[ca][mi], bf[cb][nj], acc[mi][nj], 0, 0, 0);
    }

    __syncthreads();
    #pragma unroll
    for (int nj = 0; nj < 4; ++nj) {
        int cl = nj * 16 + m16;
        float bv = bias ? bias[c0 + cl] : 0.f;
        #pragma unroll
        for (int mi = 0; mi < 2; ++mi)
            #pragma unroll
            for (int r = 0; r < 4; ++r)
                smem[(wid * 32 + mi * 16 + q * 4 + r) * 72 + cl] = f2bf(acc[mi][nj][r] + bv);
    }
    __syncthreads();
    #pragma unroll
    for (int h = 0; h < 4; ++h) {
        int idx = tid + h * 256;
        int row = idx >> 3, c8 = idx & 7;
        long long grow = rowbase + row;
        if (grow < n)
            *(short8*)(outp + grow * DH + c0 + c8 * 8) = *(const short8*)(smem + row * 72 + c8 * 8);
    }
}

// ---------- fused GEMM (K=128, full 128 cols) + LN/ELU + mW2 + softmax ----------
__global__ __launch_bounds__(256, 3) void gemm_head_k(
    const unsigned short* __restrict__ A, const unsigned short* __restrict__ Bp,
    const float* __restrict__ mb1,
    const float* __restrict__ g, const float* __restrict__ be,
    const float* __restrict__ mW2, const float* __restrict__ mb2,
    float* __restrict__ out, int n)
{
    __shared__ __align__(16) unsigned short smem[16384];
    const int tid = threadIdx.x;
    const int wid = tid >> 6, lane = tid & 63;
    const int m16 = lane & 15, q = lane >> 4;
    const int rh = wid >> 1, ch = wid & 1;
    const long long rowbase = (long long)blockIdx.x * 64;

    long long r0 = rowbase + rh * 32 + m16;       if (r0 > (long long)n - 1) r0 = n - 1;
    long long r1 = rowbase + rh * 32 + 16 + m16;  if (r1 > (long long)n - 1) r1 = n - 1;

    f32x4 acc[2][4];
    const f32x4 zero = {0.f, 0.f, 0.f, 0.f};
    #pragma unroll
    for (int mi = 0; mi < 2; ++mi)
        #pragma unroll
        for (int nj = 0; nj < 4; ++nj) acc[mi][nj] = zero;

    short8 ha[3][2];
    short8 bf[2][4];

    auto fetchA = [&](int kb, int buf) {
        ha[buf][0] = *(const short8*)(A + r0 * 128 + kb * 32 + q * 8);
        ha[buf][1] = *(const short8*)(A + r1 * 128 + kb * 32 + q * 8);
    };
    auto fetchB = [&](int kb, int buf) {
        #pragma unroll
        for (int nj = 0; nj < 4; ++nj)
            bf[buf][nj] = *(const short8*)(smem + kb * 4096 + (ch * 64 + nj * 16 + m16) * 32 + q * 8);
    };

    fetchA(0, 0);
    fetchA(1, 1);
    #pragma unroll
    for (int t = tid; t < 2048; t += 256)
        *(short8*)(smem + t * 8) = *(const short8*)(Bp + t * 8);

    // hoist per-lane mW2 values (row-invariant): 32 registers
    int k = lane & 15, seg = lane >> 4;
    float w2r0[16], w2r1[16];
    #pragma unroll
    for (int t = 0; t < 16; ++t) {
        int c = seg * 32 + 2 * t;
        w2r0[t] = mW2[c * 16 + k];
        w2r1[t] = mW2[(c + 1) * 16 + k];
    }
    float bias2 = mb2[k];
    float2 gv  = *(const float2*)(g + 2 * lane);
    float2 bev = *(const float2*)(be + 2 * lane);

    __syncthreads();

    fetchB(0, 0);
    #pragma unroll
    for (int kb = 0; kb < 4; ++kb) {
        if (kb + 2 < 4) fetchA(kb + 2, (kb + 2) % 3);
        if (kb + 1 < 4) fetchB(kb + 1, (kb + 1) & 1);
        const int ca = kb % 3, cb = kb & 1;
        #pragma unroll
        for (int mi = 0; mi < 2; ++mi)
            #pragma unroll
            for (int nj = 0; nj < 4; ++nj)
                acc[mi][nj] = __builtin_amdgcn_mfma_f32_16x16x32_bf16(ha[ca][mi], bf[cb][nj], acc[mi][nj], 0, 0, 0);
    }

    // epilogue -> LDS rows (pitch 136 shorts = 68 uints)
    __syncthreads();
    #pragma unroll
    for (int nj = 0; nj < 4; ++nj) {
        int cl = ch * 64 + nj * 16 + m16;
        float bv = mb1[cl];
        #pragma unroll
        for (int mi = 0; mi < 2; ++mi)
            #pragma unroll
            for (int r = 0; r < 4; ++r)
                smem[(rh * 32 + mi * 16 + q * 4 + r) * 136 + cl] = f2bf(acc[mi][nj][r] + bv);
    }
    __syncthreads();

    // head: wave w processes rows w*16..+16 from LDS; mW2 already in registers
    const unsigned* zl = (const unsigned*)smem;
    for (int rr = 0; rr < 16; ++rr) {
        int lrow = wid * 16 + rr;
        long long grow = rowbase + lrow;
        if (grow >= n) break;
        unsigned u = zl[lrow * 68 + lane];
        float o0, o1; ln_pair(bfl(u), bfh(u), o0, o1);
        float z0 = elu(o0 * gv.x + bev.x);
        float z1 = elu(o1 * gv.y + bev.y);
        float acch = 0.f;
        #pragma unroll
        for (int t = 0; t < 16; ++t) {
            int srcl = seg * 16 + t;
            float zz0 = __shfl(z0, srcl, 64);
            float zz1 = __shfl(z1, srcl, 64);
            acch = fmaf(zz0, w2r0[t], acch);
            acch = fmaf(zz1, w2r1[t], acch);
        }
        acch += __shfl_xor(acch, 32, 64);
        acch += __shfl_xor(acch, 16, 64);
        float hk = acch + bias2;
        float mx = hk;
        #pragma unroll
        for (int o = 8; o > 0; o >>= 1) mx = fmaxf(mx, __shfl_xor(mx, o, 64));
        float e = expf(hk - mx);
        float s = e;
        #pragma unroll
        for (int o = 8; o > 0; o >>= 1) s += __shfl_xor(s, o, 64);
        if (lane < 16) out[grow * 16 + k] = e / s;
    }
}

// ---------- CSR gather (bf16 rows), one wave per row, 8 loads in flight ----------
__device__ __forceinline__ void gather_row(
    const unsigned* __restrict__ hw, const int2* __restrict__ csr,
    int beg, int end, int lane, float& o0, float& o1)
{
    float a0 = 0.f, a1 = 0.f, b0 = 0.f, b1 = 0.f;
    float c0 = 0.f, c1 = 0.f, d0 = 0.f, d1 = 0.f;
    int p = beg;
    for (; p + 7 < end; p += 8) {
        int2 e0 = csr[p],     e1 = csr[p + 1], e2 = csr[p + 2], e3 = csr[p + 3];
        int2 e4 = csr[p + 4], e5 = csr[p + 5], e6 = csr[p + 6], e7 = csr[p + 7];
        unsigned u0 = hw[(long long)e0.x * 64 + lane];
        unsigned u1 = hw[(long long)e1.x * 64 + lane];
        unsigned u2 = hw[(long long)e2.x * 64 + lane];
        unsigned u3 = hw[(long long)e3.x * 64 + lane];
        unsigned u4 = hw[(long long)e4.x * 64 + lane];
        unsigned u5 = hw[(long long)e5.x * 64 + lane];
        unsigned u6 = hw[(long long)e6.x * 64 + lane];
        unsigned u7 = hw[(long long)e7.x * 64 + lane];
        float w0 = __int_as_float(e0.y), w1 = __int_as_float(e1.y);
        float w2 = __int_as_float(e2.y), w3 = __int_as_float(e3.y);
        float w4 = __int_as_float(e4.y), w5 = __int_as_float(e5.y);
        float w6 = __int_as_float(e6.y), w7 = __int_as_float(e7.y);
        a0 = fmaf(w0, bfl(u0), a0);  a1 = fmaf(w0, bfh(u0), a1);
        b0 = fmaf(w1, bfl(u1), b0);  b1 = fmaf(w1, bfh(u1), b1);
        c0 = fmaf(w2, bfl(u2), c0);  c1 = fmaf(w2, bfh(u2), c1);
        d0 = fmaf(w3, bfl(u3), d0);  d1 = fmaf(w3, bfh(u3), d1);
        a0 = fmaf(w4, bfl(u4), a0);  a1 = fmaf(w4, bfh(u4), a1);
        b0 = fmaf(w5, bfl(u5), b0);  b1 = fmaf(w5, bfh(u5), b1);
        c0 = fmaf(w6, bfl(u6), c0);  c1 = fmaf(w6, bfh(u6), c1);
        d0 = fmaf(w7, bfl(u7), d0);  d1 = fmaf(w7, bfh(u7), d1);
    }
    for (; p + 3 < end; p += 4) {
        int2 e0 = csr[p], e1 = csr[p + 1], e2 = csr[p + 2], e3 = csr[p + 3];
        unsigned u0 = hw[(long long)e0.x * 64 + lane];
        unsigned u1 = hw[(long long)e1.x * 64 + lane];
        unsigned u2 = hw[(long long)e2.x * 64 + lane];
        unsigned u3 = hw[(long long)e3.x * 64 + lane];
        float w0 = __int_as_float(e0.y), w1 = __int_as_float(e1.y);
        float w2 = __int_as_float(e2.y), w3 = __int_as_float(e3.y);
        a0 = fmaf(w0, bfl(u0), a0);  a1 = fmaf(w0, bfh(u0), a1);
        b0 = fmaf(w1, bfl(u1), b0);  b1 = fmaf(w1, bfh(u1), b1);
        c0 = fmaf(w2, bfl(u2), c0);  c1 = fmaf(w2, bfh(u2), c1);
        d0 = fmaf(w3, bfl(u3), d0);  d1 = fmaf(w3, bfh(u3), d1);
    }
    for (; p < end; ++p) {
        int2 e0 = csr[p];
        unsigned u0 = hw[(long long)e0.x * 64 + lane];
        float w0 = __int_as_float(e0.y);
        a0 = fmaf(w0, bfl(u0), a0);
        a1 = fmaf(w0, bfh(u0), a1);
    }
    o0 = (a0 + b0) + (c0 + d0);
    o1 = (a1 + b1) + (c1 + d1);
}

// layer 1: h = elu(LN(gather + dinv^2*hw + b1)) + LN(proj)
__global__ __launch_bounds__(256) void gfuse1_k(
    const unsigned* __restrict__ hw, const unsigned* __restrict__ proj,
    const int* __restrict__ rowptr, const int2* __restrict__ csr,
    const float* __restrict__ dinv,
    const float* __restrict__ b1, const float* __restrict__ g1, const float* __restrict__ be1,
    const float* __restrict__ rg, const float* __restrict__ rbe,
    unsigned* __restrict__ hout, int n)
{
    int row = blockIdx.x * 4 + (threadIdx.x >> 6);
    if (row >= n) return;
    int lane = threadIdx.x & 63;
    float a0, a1;
    gather_row(hw, csr, rowptr[row], rowptr[row + 1], lane, a0, a1);
    long long off = (long long)row * 64;
    float di = dinv[row], sl = di * di;
    unsigned us = hw[off + lane];
    float2 bv  = *(const float2*)(b1 + 2 * lane);
    float2 gv  = *(const float2*)(g1 + 2 * lane);
    float2 bev = *(const float2*)(be1 + 2 * lane);
    float2 rgv = *(const float2*)(rg + 2 * lane);
    float2 rbv = *(const float2*)(rbe + 2 * lane);
    float v0 = a0 + sl * bfl(us) + bv.x;
    float v1 = a1 + sl * bfh(us) + bv.y;
    float o0, o1; ln_pair(v0, v1, o0, o1);
    float t0 = elu(o0 * gv.x + bev.x);
    float t1 = elu(o1 * gv.y + bev.y);
    unsigned up = proj[off + lane];
    float q0, q1; ln_pair(bfl(up), bfh(up), q0, q1);
    hout[off + lane] = pack_bf2(t0 + q0 * rgv.x + rbv.x, t1 + q1 * rgv.y + rbv.y);
}

// layer 2: h2 = elu(LN(gather + dinv^2*hw + b2)) + hprev
__global__ __launch_bounds__(256) void gfuse2_k(
    const unsigned* __restrict__ hw, const unsigned* __restrict__ hprev,
    const int* __restrict__ rowptr, const int2* __restrict__ csr,
    const float* __restrict__ dinv,
    const float* __restrict__ b2, const float* __restrict__ g2, const float* __restrict__ be2,
    unsigned* __restrict__ h2, int n)
{
    int row = blockIdx.x * 4 + (threadIdx.x >> 6);
    if (row >= n) return;
    int lane = threadIdx.x & 63;
    float a0, a1;
    gather_row(hw, csr, rowptr[row], rowptr[row + 1], lane, a0, a1);
    long long off = (long long)row * 64;
    float di = dinv[row], sl = di * di;
    unsigned us = hw[off + lane];
    float2 bv  = *(const float2*)(b2 + 2 * lane);
    float2 gv  = *(const float2*)(g2 + 2 * lane);
    float2 bev = *(const float2*)(be2 + 2 * lane);
    float v0 = a0 + sl * bfl(us) + bv.x;
    float v1 = a1 + sl * bfh(us) + bv.y;
    float o0, o1; ln_pair(v0, v1, o0, o1);
    float t0 = elu(o0 * gv.x + bev.x);
    float t1 = elu(o1 * gv.y + bev.y);
    unsigned uh = hprev[off + lane];
    h2[off + lane] = pack_bf2(t0 + bfl(uh), t1 + bfh(uh));
}

// ---------- launcher ----------
static inline size_t align16(size_t x) { return (x + 15) & ~(size_t)15; }

extern "C" void kernel_launch(void* const* d_in, const int* in_sizes, int n_in,
                              void* d_out, int out_size, void* d_ws, size_t ws_size,
                              hipStream_t stream)
{
    const float* x   = (const float*)d_in[0];
    const int*   ei  = (const int*)d_in[1];
    const float* W1  = (const float*)d_in[2];
    const float* b1  = (const float*)d_in[3];
    const float* g1  = (const float*)d_in[4];
    const float* be1 = (const float*)d_in[5];
    const float* W2  = (const float*)d_in[6];
    const float* b2  = (const float*)d_in[7];
    const float* g2  = (const float*)d_in[8];
    const float* be2 = (const float*)d_in[9];
    const float* rW  = (const float*)d_in[10];
    const float* rb  = (const float*)d_in[11];
    const float* rg  = (const float*)d_in[12];
    const float* rbe = (const float*)d_in[13];
    const float* mW1 = (const float*)d_in[14];
    const float* mb1 = (const float*)d_in[15];
    const float* mg  = (const float*)d_in[16];
    const float* mbe = (const float*)d_in[17];
    const float* mW2 = (const float*)d_in[18];
    const float* mb2 = (const float*)d_in[19];
    float* out = (float*)d_out;

    const int n = in_sizes[0] / 384;
    const int E = in_sizes[1] / 2;
    const int* src = ei;
    const int* dst = ei + E;

    char* w = (char*)d_ws;
    int* deg     = (int*)w;   w += align16((size_t)n * 4);
    int* rowptr  = (int*)w;   w += align16((size_t)(n + 1) * 4);
    int* cursor  = (int*)w;   w += align16((size_t)n * 4);
    float* dinv  = (float*)w; w += align16((size_t)n * 4);
    int* bsum    = (int*)w;   w += align16((size_t)1024 * 4);
    int2* csr    = (int2*)w;  w += align16((size_t)E * 8);
    unsigned short* xb   = (unsigned short*)w; w += align16((size_t)n * 384 * 2);
    unsigned short* hw1  = (unsigned short*)w; w += align16((size_t)n * DH * 2);
    unsigned short* proj = (unsigned short*)w; w += align16((size_t)n * DH * 2);
    unsigned short* hbuf = (unsigned short*)w; w += align16((size_t)n * DH * 2);
    unsigned short* Wp   = (unsigned short*)w; w += align16((size_t)131072 * 2);
    unsigned short* Wp1 = Wp;
    unsigned short* Wpr = Wp + 49152;
    unsigned short* Wp2 = Wp + 98304;
    unsigned short* WpM = Wp + 114688;
    unsigned short* hw2  = hw1;   // free after gfuse1
    unsigned short* h2   = proj;  // free after gfuse1

    int gE = (E + 255) / 256;
    int gN = (n + 255) / 256;
    int nb = (n + 1023) / 1024;
    dim3 gGd((n + 127) / 128, 4);   // dual (matrix x col-half)
    dim3 gGs((n + 127) / 128, 2);   // single
    int gRow4 = (n + 3) / 4;
    int gH = (n + 63) / 64;

    // x -> bf16 (pure streaming, also zeroes deg) + weight repack
    conv_x_k<<<2048, 256, 0, stream>>>(x, xb, (long long)n * 48, deg, n);
    repack_all_k<<<512, 256, 0, stream>>>(W1, rW, W2, mW1, Wp);

    // CSR build
    deg_count_k<<<gE, 256, 0, stream>>>(dst, deg, E);
    scan_part_k<<<nb, 1024, 0, stream>>>(deg, rowptr, bsum, dinv, n);
    scan_top_k<<<1, 64, 0, stream>>>(bsum, rowptr + n, nb);
    scan_add_k<<<gN, 256, 0, stream>>>(bsum, rowptr, cursor, n);
    fill_k<<<gE, 256, 0, stream>>>(src, dst, dinv, cursor, csr, E);

    // layer 1 (dual: hw1 = xb@W1, proj = xb@rW + rb)
    mfma_gemm<384, 2><<<gGd, 256, 0, stream>>>(xb, Wp1, nullptr, Wpr, rb, hw1, proj, n);
    gfuse1_k<<<gRow4, 256, 0, stream>>>((unsigned*)hw1, (unsigned*)proj, rowptr, csr, dinv,
                                        b1, g1, be1, rg, rbe, (unsigned*)hbuf, n);

    // layer 2
    mfma_gemm<128, 1><<<gGs, 256, 0, stream>>>(hbuf, Wp2, nullptr, nullptr, nullptr, hw2, nullptr, n);
    gfuse2_k<<<gRow4, 256, 0, stream>>>((unsigned*)hw2, (unsigned*)hbuf, rowptr, csr, dinv,
                                        b2, g2, be2, (unsigned*)h2, n);

    // fused MLP head + softmax
    gemm_head_k<<<gH, 256, 0, stream>>>(h2, WpM, mb1, mg, mbe, mW2, mb2, out, n);
}